// Round 2
// baseline (374.854 us; speedup 1.0000x reference)
//
#include <hip/hip_runtime.h>
#include <hip/hip_fp16.h>

typedef int v4i __attribute__((ext_vector_type(4)));

#define AS1C(p) ((const __attribute__((address_space(1))) void*)(p))
#define AS3(p)  ((__attribute__((address_space(3))) void*)(p))

// ---------------------------------------------------------------------------
// Stage a 128-row x 64-byte tile from global (row-major, leading dim ld) into
// LDS via global_load_lds (width 16). LDS layout is linear per chunk; the
// 16B slot within each 64B row is XOR-swizzled on the GLOBAL side
// (slot ^ ((row>>1)&3)) so the MFMA-fragment ds_read_b128 is ~2-way
// conflict-free. Reader applies the same XOR (involution).
// ---------------------------------------------------------------------------
__device__ __forceinline__ void stage_tile(const signed char* __restrict__ g, long long ld,
                                           long long rmax, long long r0, int k0,
                                           char* lds, int tid) {
  const int wave = tid >> 6, lane = tid & 63;
#pragma unroll
  for (int p = 0; p < 2; ++p) {
    const int chunk = wave * 2 + p;           // 8 chunks of 1 KiB = 128x64
    const int row = chunk * 16 + (lane >> 2); // 4 lanes per 64B row
    const int slot = lane & 3;                // 16B slot (linear, LDS side)
    const int gslot = slot ^ ((row >> 1) & 3);
    long long rg = r0 + row;
    if (rg > rmax) rg = rmax;                 // clamp (M tail); stores guarded later
    const signed char* src = g + rg * ld + (long long)k0 + gslot * 16;
    char* dst = lds + chunk * 1024;           // wave-uniform base; HW adds lane*16
    __builtin_amdgcn_global_load_lds(AS1C(src), AS3(dst), 16, 0, 0);
  }
}

// ---------------------------------------------------------------------------
// 128x128 int8 GEMM tile, C = A[M,K] * B[N,K]^T, 4 waves (2x2 of 64x64),
// mfma_i32_16x16x64_i8, double-buffered LDS staging via global_load_lds.
// EPI 0: fc1 epilogue (dequant+bias -> fp16 -> GELU -> g fp16 + atomicMax amax)
// EPI 1: fc2 epilogue (dequant with fp16(amax/127) + bias -> fp16-rounded f32 out)
// NOTE: scale_tok / bias are FLOAT32 (harness converts fp16 inputs to f32).
// ---------------------------------------------------------------------------
template <int EPI>
__launch_bounds__(256, 2)
__global__ void gemm_i8(const signed char* __restrict__ A, const signed char* __restrict__ Bw,
                        int M, int N, int K,
                        const float* __restrict__ scale_tok, const float* __restrict__ wsc,
                        const float* __restrict__ bias,
                        __half* __restrict__ gout, unsigned int* __restrict__ amax,
                        float* __restrict__ fout) {
  __shared__ __align__(16) char lds[2][2][128 * 64];
  const int tid = threadIdx.x;
  const int lane = tid & 63, wave = tid >> 6;
  const int wrow = (wave >> 1) * 64, wcol = (wave & 1) * 64;
  const long long t0 = (long long)blockIdx.y * 128;
  const long long n0 = (long long)blockIdx.x * 128;

  v4i acc[4][4] = {};

  stage_tile(A, K, (long long)M - 1, t0, 0, lds[0][0], tid);
  stage_tile(Bw, K, (long long)N - 1, n0, 0, lds[0][1], tid);
  __syncthreads();

  const int nk = K >> 6;
  int cur = 0;
  const int srow = lane & 15, sseg = lane >> 4;
  for (int kt = 0; kt < nk; ++kt) {
    if (kt + 1 < nk) {
      stage_tile(A, K, (long long)M - 1, t0, (kt + 1) << 6, lds[cur ^ 1][0], tid);
      stage_tile(Bw, K, (long long)N - 1, n0, (kt + 1) << 6, lds[cur ^ 1][1], tid);
    }
    v4i af[4], bf[4];
#pragma unroll
    for (int mi = 0; mi < 4; ++mi) {
      const int r = wrow + mi * 16 + srow;
      const int sl = sseg ^ ((r >> 1) & 3);
      af[mi] = *(const v4i*)&lds[cur][0][r * 64 + sl * 16];
    }
#pragma unroll
    for (int ni = 0; ni < 4; ++ni) {
      const int r = wcol + ni * 16 + srow;
      const int sl = sseg ^ ((r >> 1) & 3);
      bf[ni] = *(const v4i*)&lds[cur][1][r * 64 + sl * 16];
    }
#pragma unroll
    for (int mi = 0; mi < 4; ++mi)
#pragma unroll
      for (int ni = 0; ni < 4; ++ni)
        acc[mi][ni] = __builtin_amdgcn_mfma_i32_16x16x64_i8(af[mi], bf[ni], acc[mi][ni], 0, 0, 0);
    __syncthreads();
    cur ^= 1;
  }

  if (EPI == 0) {
#pragma unroll
    for (int mi = 0; mi < 4; ++mi) {
#pragma unroll
      for (int j = 0; j < 4; ++j) {
        const long long t = t0 + wrow + mi * 16 + (lane >> 4) * 4 + j;
        const bool valid = (t < M);
        const float st = valid ? scale_tok[t] : 0.f;
        float rowmax = 0.f;
#pragma unroll
        for (int ni = 0; ni < 4; ++ni) {
          const long long c = n0 + wcol + ni * 16 + (lane & 15);
          float v = (float)acc[mi][ni][j] * st * wsc[c] + bias[c];
          v = __half2float(__float2half(v));  // fc1 rounds to fp16 (reference)
          const float gl = 0.5f * v * (1.f + erff(v * 0.70710678118654752f));
          rowmax = fmaxf(rowmax, fabsf(gl));
          if (valid) gout[t * (long long)N + c] = __float2half(gl);
        }
        // reduce row max across the 16 lanes sharing this output row
#pragma unroll
        for (int m = 1; m < 16; m <<= 1) rowmax = fmaxf(rowmax, __shfl_xor(rowmax, m));
        if (valid && (lane & 15) == 0) atomicMax(&amax[t], __float_as_uint(rowmax));
      }
    }
  } else {
#pragma unroll
    for (int mi = 0; mi < 4; ++mi) {
#pragma unroll
      for (int j = 0; j < 4; ++j) {
        const long long t = t0 + wrow + mi * 16 + (lane >> 4) * 4 + j;
        if (t < M) {
          const float am = __uint_as_float(amax[t]);
          const float st = __half2float(__float2half(am * (1.f / 127.f)));  // scale_act via fp16
#pragma unroll
          for (int ni = 0; ni < 4; ++ni) {
            const long long c = n0 + wcol + ni * 16 + (lane & 15);
            const float v = (float)acc[mi][ni][j] * st * wsc[c] + bias[c];
            fout[t * (long long)N + c] = __half2float(__float2half(v));  // fp16-rounded, f32 out
          }
        }
      }
    }
  }
}

// ---------------------------------------------------------------------------
// int32 -> int8 packing for x, w1, w2 (+ zero the amax buffer each call)
// ---------------------------------------------------------------------------
__global__ void pack_all(const int* __restrict__ a, const int* __restrict__ b,
                         const int* __restrict__ c,
                         signed char* __restrict__ pa, signed char* __restrict__ pb,
                         signed char* __restrict__ pc,
                         unsigned int* __restrict__ amax,
                         long long na, long long nb, long long nc, int T) {
  const long long gid = blockIdx.x * (long long)blockDim.x + threadIdx.x;
  if (gid < T) amax[gid] = 0u;
  const long long n4a = na >> 2, n4b = nb >> 2, n4c = nc >> 2;
  const long long tot = n4a + n4b + n4c;
  const long long stride = (long long)gridDim.x * blockDim.x;
  for (long long u = gid; u < tot; u += stride) {
    const int* src; signed char* dst; long long loc;
    if (u < n4a)            { src = a; dst = pa; loc = u; }
    else if (u < n4a + n4b) { src = b; dst = pb; loc = u - n4a; }
    else                    { src = c; dst = pc; loc = u - n4a - n4b; }
    const int4 v = *(const int4*)(src + (loc << 2));
    const unsigned out = (unsigned)(v.x & 0xff) | ((unsigned)(v.y & 0xff) << 8) |
                         ((unsigned)(v.z & 0xff) << 16) | ((unsigned)(v.w & 0xff) << 24);
    *(unsigned*)(dst + (loc << 2)) = out;
  }
}

// ---------------------------------------------------------------------------
// per-token dynamic int8 quantization of the GELU output
// ---------------------------------------------------------------------------
__global__ void gelu_quant(const __half* __restrict__ g, const unsigned int* __restrict__ amax,
                           signed char* __restrict__ q, long long total, int I) {
  const long long nchunk = total >> 3;
  const long long stride = (long long)gridDim.x * blockDim.x;
  for (long long c = blockIdx.x * (long long)blockDim.x + threadIdx.x; c < nchunk; c += stride) {
    const long long base = c << 3;  // 8 elems, never crosses a row (I % 8 == 0)
    const int t = (int)(base / I);
    const float am = __uint_as_float(amax[t]);
    const float s = fmaxf(__half2float(__float2half(am * (1.f / 127.f))), 1e-8f);
    const float inv = 1.f / s;
    const int4 raw = *(const int4*)(g + base);
    const __half2* h2 = (const __half2*)&raw;
    union { signed char b[8]; int2 v; } u;
#pragma unroll
    for (int k = 0; k < 4; ++k) {
      const float2 f = __half22float2(h2[k]);
      const float q0 = fminf(fmaxf(rintf(f.x * inv), -128.f), 127.f);
      const float q1 = fminf(fmaxf(rintf(f.y * inv), -128.f), 127.f);
      u.b[k * 2]     = (signed char)(int)q0;
      u.b[k * 2 + 1] = (signed char)(int)q1;
    }
    *(int2*)(q + base) = u.v;
  }
}

extern "C" void kernel_launch(void* const* d_in, const int* in_sizes, int n_in,
                              void* d_out, int out_size, void* d_ws, size_t ws_size,
                              hipStream_t stream) {
  const int* hs = (const int*)d_in[0];
  const float* scale_in = (const float*)d_in[1];   // fp16 in reference -> f32 buffer
  const int* w1 = (const int*)d_in[2];
  const float* w1s = (const float*)d_in[3];
  const float* b1 = (const float*)d_in[4];         // fp16 -> f32
  const int* w2 = (const int*)d_in[5];
  const float* w2s = (const float*)d_in[6];
  const float* b2 = (const float*)d_in[7];         // fp16 -> f32

  const int T = in_sizes[1];        // 2050
  const int I = in_sizes[3];        // 12800
  const int H = in_sizes[6];        // 3200

  // workspace carve-up (amax first; all offsets 16B-aligned for these shapes)
  char* ws = (char*)d_ws;
  unsigned int* amax = (unsigned int*)ws;                    // T u32 (pad to 16KB)
  signed char* px  = (signed char*)(ws + 16384);             // T*H
  signed char* pw1 = px + (size_t)T * H;                     // I*H
  signed char* pw2 = pw1 + (size_t)I * H;                    // H*I
  __half* gbuf = (__half*)(pw2 + (size_t)H * I);             // T*I fp16
  signed char* qbuf = (signed char*)(gbuf + (size_t)T * I);  // T*I

  const long long nx = (long long)T * H, nw1 = (long long)I * H, nw2 = (long long)H * I;

  pack_all<<<2048, 256, 0, stream>>>(hs, w1, w2, px, pw1, pw2, amax, nx, nw1, nw2, T);

  dim3 g1(I / 128, (T + 127) / 128);
  gemm_i8<0><<<g1, 256, 0, stream>>>(px, pw1, T, I, H, scale_in, w1s, b1, gbuf, amax, nullptr);

  gelu_quant<<<2048, 256, 0, stream>>>(gbuf, amax, qbuf, (long long)T * I, I);

  dim3 g2(H / 128, (T + 127) / 128);
  gemm_i8<1><<<g2, 256, 0, stream>>>(qbuf, pw2, T, H, I, nullptr, w2s, b2, nullptr, amax, (float*)d_out);
}